// Round 13
// baseline (178.258 us; speedup 1.0000x reference)
//
#include <hip/hip_runtime.h>
#include <math.h>

// Problem constants (B=1, T=1024, E=512, H=8, D=64, M=8, R=1, P=32, CHUNK=128)
// Feature dim F = P*M = 256, flattened f = p*8 + m (consistent everywhere).

// ---------- Split-K partial GEMM: part[s][M][N] = A[M,ks]@W[N,ks]^T ----------
// 64x64 tile, 4x4 micro-tile, double-buffered LDS, ONE barrier per K-slice.
__global__ __launch_bounds__(256) void gemm_part_kernel(
    const float* __restrict__ A, const float* __restrict__ W,
    float* __restrict__ part, int M, int N, int K, int Kc)
{
    __shared__ float a_t[2][16][68];   // [buf][k][row]
    __shared__ float w_t[2][16][68];
    const int tid = threadIdx.x;
    const int n0 = blockIdx.x * 64;
    const int m0 = blockIdx.y * 64;
    const int sk = blockIdx.z;
    const int kb = sk * Kc;
    const int tx = tid & 15, ty = tid >> 4;
    const int lrow = tid >> 2;        // 0..63
    const int lk4  = (tid & 3) * 4;   // 0,4,8,12
    float acc[4][4];
#pragma unroll
    for (int i = 0; i < 4; ++i)
#pragma unroll
        for (int j = 0; j < 4; ++j) acc[i][j] = 0.f;

    const float* Ap = &A[(m0 + lrow) * K + kb + lk4];
    const float* Wp = &W[(n0 + lrow) * K + kb + lk4];
    float4 ra = *(const float4*)Ap;
    float4 rw = *(const float4*)Wp;
    a_t[0][lk4 + 0][lrow] = ra.x; a_t[0][lk4 + 1][lrow] = ra.y;
    a_t[0][lk4 + 2][lrow] = ra.z; a_t[0][lk4 + 3][lrow] = ra.w;
    w_t[0][lk4 + 0][lrow] = rw.x; w_t[0][lk4 + 1][lrow] = rw.y;
    w_t[0][lk4 + 2][lrow] = rw.z; w_t[0][lk4 + 3][lrow] = rw.w;
    __syncthreads();

    int cur = 0;
    for (int k0 = 16; k0 <= Kc; k0 += 16) {
        const bool more = (k0 < Kc);
        if (more) {
            ra = *(const float4*)(Ap + k0);
            rw = *(const float4*)(Wp + k0);
        }
#pragma unroll
        for (int k = 0; k < 16; ++k) {
            float4 af = *(const float4*)&a_t[cur][k][ty * 4];
            float4 wf = *(const float4*)&w_t[cur][k][tx * 4];
            acc[0][0] += af.x * wf.x; acc[0][1] += af.x * wf.y;
            acc[0][2] += af.x * wf.z; acc[0][3] += af.x * wf.w;
            acc[1][0] += af.y * wf.x; acc[1][1] += af.y * wf.y;
            acc[1][2] += af.y * wf.z; acc[1][3] += af.y * wf.w;
            acc[2][0] += af.z * wf.x; acc[2][1] += af.z * wf.y;
            acc[2][2] += af.z * wf.z; acc[2][3] += af.z * wf.w;
            acc[3][0] += af.w * wf.x; acc[3][1] += af.w * wf.y;
            acc[3][2] += af.w * wf.z; acc[3][3] += af.w * wf.w;
        }
        if (more) {
            const int nxt = cur ^ 1;
            a_t[nxt][lk4 + 0][lrow] = ra.x; a_t[nxt][lk4 + 1][lrow] = ra.y;
            a_t[nxt][lk4 + 2][lrow] = ra.z; a_t[nxt][lk4 + 3][lrow] = ra.w;
            w_t[nxt][lk4 + 0][lrow] = rw.x; w_t[nxt][lk4 + 1][lrow] = rw.y;
            w_t[nxt][lk4 + 2][lrow] = rw.z; w_t[nxt][lk4 + 3][lrow] = rw.w;
            __syncthreads();
            cur = nxt;
        }
    }
#pragma unroll
    for (int i = 0; i < 4; ++i) {
        float4 o = make_float4(acc[i][0], acc[i][1], acc[i][2], acc[i][3]);
        *(float4*)&part[((size_t)sk * M + m0 + ty * 4 + i) * N + n0 + tx * 4] = o;
    }
}

// ---------- Reduce split-K partials + bias ----------
__global__ __launch_bounds__(256) void reduce_bias_kernel(
    const float* __restrict__ part, const float* __restrict__ bias,
    float* __restrict__ C, int MN, int N, int S)
{
    const int i4 = (blockIdx.x * 256 + threadIdx.x) * 4;
    if (i4 >= MN) return;
    float4 acc = *(const float4*)&part[i4];
    for (int s = 1; s < S; ++s) {
        float4 p = *(const float4*)&part[(size_t)s * MN + i4];
        acc.x += p.x; acc.y += p.y; acc.z += p.z; acc.w += p.w;
    }
    float4 b = *(const float4*)&bias[i4 % N];   // N % 4 == 0
    acc.x += b.x; acc.y += b.y; acc.z += b.z; acc.w += b.w;
    *(float4*)&C[i4] = acc;
}

// ---------- Features: phi_q/phi_k[h][t][256] from qkv ----------
__global__ __launch_bounds__(256) void features_kernel(
    const float* __restrict__ qkv, const float* __restrict__ omega,
    const float* __restrict__ W_poly, const float* __restrict__ qn,
    const float* __restrict__ qw, float* __restrict__ phi_q,
    float* __restrict__ phi_k)
{
    __shared__ float xn[4][2][64];
    __shared__ float poly[4][2][32];
    __shared__ float prf[4][2][8];
    const int tid = threadIdx.x;
    const int w = tid >> 6;
    const int lane = tid & 63;
    const int item = blockIdx.x * 4 + w;     // 0..8191
    const int h = item >> 10;
    const int t = item & 1023;

    float xq = qkv[t * 1536 + h * 64 + lane];
    float xk = qkv[t * 1536 + 512 + h * 64 + lane];
    float sq = xq * xq, sk = xk * xk;
#pragma unroll
    for (int o = 32; o; o >>= 1) { sq += __shfl_xor(sq, o); sk += __shfl_xor(sk, o); }
    float xnq = xq / fmaxf(sqrtf(sq), 1e-12f);
    float xnk = xk / fmaxf(sqrtf(sk), 1e-12f);
    xn[w][0][lane] = xnq;
    xn[w][1][lane] = xnk;
    __syncthreads();

    {
        const int which = lane >> 5;
        const int p = lane & 31;
        float pacc = 0.f;
#pragma unroll 8
        for (int d = 0; d < 64; ++d)
            pacc += xn[w][which][d] * W_poly[(h * 64 + d) * 32 + p];
        poly[w][which][p] = pacc;
    }
    if (lane < 16) {
        const int wh2 = lane >> 3, m = lane & 7;
        float pr = 0.f;
#pragma unroll 8
        for (int d = 0; d < 64; ++d)
            pr += xn[w][wh2][d] * omega[(h * 64 + d) * 8 + m];
        float s0 = qn[0];
        float sqrt2s = sqrtf(2.f * fmaxf(s0, 0.f));
        float sqw = sqrtf(fmaxf(qw[0], 0.f));
        float z = fminf(fmaxf(pr * sqrt2s - s0, -20.f), 20.f);
        prf[w][wh2][m] = expf(z) * 0.3535533905932738f * sqw;
    }
    __syncthreads();

    const int pp = lane >> 1;
    const int mb = (lane & 1) * 4;
    float qp = poly[w][0][pp], kp = poly[w][1][pp];
    float4 oq, ok;
    oq.x = qp * prf[w][0][mb + 0]; oq.y = qp * prf[w][0][mb + 1];
    oq.z = qp * prf[w][0][mb + 2]; oq.w = qp * prf[w][0][mb + 3];
    ok.x = kp * prf[w][1][mb + 0]; ok.y = kp * prf[w][1][mb + 1];
    ok.z = kp * prf[w][1][mb + 2]; ok.w = kp * prf[w][1][mb + 3];
    *(float4*)&phi_q[((h << 10) + t) * 256 + lane * 4] = oq;
    *(float4*)&phi_k[((h << 10) + t) * 256 + lane * 4] = ok;
}

// ---------- Chunk sums ----------
__global__ __launch_bounds__(256) void chunksum_kernel(
    const float* __restrict__ phi_k, const float* __restrict__ qkv,
    float* __restrict__ S_chunk, float* __restrict__ z_chunk)
{
    __shared__ float pk[128][64];
    __shared__ float vv[128][64];
    const int tid = threadIdx.x;
    const int h  = blockIdx.x >> 5;
    const int c  = (blockIdx.x >> 2) & 7;
    const int fg = blockIdx.x & 3;
    const int f0 = fg * 64;

#pragma unroll
    for (int i = 0; i < 8; ++i) {
        int e4 = i * 256 + tid;
        int s = e4 >> 4;
        int f4 = (e4 & 15) * 4;
        *(float4*)&pk[s][f4] =
            *(const float4*)&phi_k[((h << 10) + c * 128 + s) * 256 + f0 + f4];
    }
#pragma unroll
    for (int i = 0; i < 8; ++i) {
        int e4 = i * 256 + tid;
        int s = e4 >> 4;
        int d4 = (e4 & 15) * 4;
        *(float4*)&vv[s][d4] =
            *(const float4*)&qkv[(c * 128 + s) * 1536 + 1024 + h * 64 + d4];
    }
    __syncthreads();

    const int tx = tid & 15;
    const int ty = tid >> 4;
    float acc[4][4];
#pragma unroll
    for (int i = 0; i < 4; ++i)
#pragma unroll
        for (int j = 0; j < 4; ++j) acc[i][j] = 0.f;

    for (int s = 0; s < 128; ++s) {
        float4 pv = *(const float4*)&pk[s][ty * 4];
        float4 v4 = *(const float4*)&vv[s][tx * 4];
        acc[0][0] += pv.x * v4.x; acc[0][1] += pv.x * v4.y;
        acc[0][2] += pv.x * v4.z; acc[0][3] += pv.x * v4.w;
        acc[1][0] += pv.y * v4.x; acc[1][1] += pv.y * v4.y;
        acc[1][2] += pv.y * v4.z; acc[1][3] += pv.y * v4.w;
        acc[2][0] += pv.z * v4.x; acc[2][1] += pv.z * v4.y;
        acc[2][2] += pv.z * v4.z; acc[2][3] += pv.z * v4.w;
        acc[3][0] += pv.w * v4.x; acc[3][1] += pv.w * v4.y;
        acc[3][2] += pv.w * v4.z; acc[3][3] += pv.w * v4.w;
    }

    if (tid < 64) {
        float zacc = 0.f;
        for (int s = 0; s < 128; ++s) zacc += pk[s][tid];
        z_chunk[(h * 8 + c) * 256 + f0 + tid] = zacc;
    }

#pragma unroll
    for (int i = 0; i < 4; ++i) {
        float4 o = make_float4(acc[i][0], acc[i][1], acc[i][2], acc[i][3]);
        *(float4*)&S_chunk[((h * 8 + c) * 256 + f0 + ty * 4 + i) * 64 + tx * 4] = o;
    }
}

// ---------- Exclusive prefix over chunks ----------
__global__ __launch_bounds__(256) void scan_kernel(
    const float* __restrict__ S_chunk, const float* __restrict__ z_chunk,
    float* __restrict__ S_prev, float* __restrict__ z_prev)
{
    int gid = blockIdx.x * 256 + threadIdx.x;
    if (gid < 8 * 256 * 64) {
        int h = gid >> 14;
        int r = gid & 16383;
        float acc = 0.f;
#pragma unroll
        for (int c = 0; c < 8; ++c) {
            int idx = ((h * 8 + c) << 14) + r;
            S_prev[idx] = acc;
            acc += S_chunk[idx];
        }
    }
    if (gid < 2048) {
        int h = gid >> 8, f = gid & 255;
        float acc = 0.f;
#pragma unroll
        for (int c = 0; c < 8; ++c) {
            int idx = (h * 8 + c) * 256 + f;
            z_prev[idx] = acc;
            acc += z_chunk[idx];
        }
    }
}

// ---------- Attention output per (h, c, y): 16 rows x 64 d ----------
// Grid 64x8 = 512 blocks (2-3 blocks/CU co-resident: inter-block TLP hides
// barrier/latency stalls — round-11 lesson: 256 blocks = 1/CU had none).
// LDS ~42KB (v_lds dropped; tail reads V from global, coalesced across lanes
// — round-7 counters showed FETCH flat for global V; its regression was the
// VGPR cap, not the V reads). Register-prefetch ft-pipeline (round-8 form).
__global__ __launch_bounds__(512, 2) void attn_kernel(
    const float* __restrict__ phi_q, const float* __restrict__ phi_k,
    const float* __restrict__ qkv, const float* __restrict__ S_prev,
    const float* __restrict__ z_prev, float* __restrict__ attn)
{
    __shared__ float A_lds[16 * 132];      //  8.4 KB [t_local][s]
    __shared__ float phq_t[32][20];        //  2.5 KB [f][t] (16 + 4 pad)
    __shared__ float phk_t[32][132];       // 16.9 KB [f][s]
    __shared__ float Sst[32][68];          //  8.7 KB [f][d] (+4 pad)
    __shared__ float ctx_lds[16][64];      //  4.0 KB [t_local][d]
    __shared__ float z_lds[256];
    __shared__ float den_lds[16];
    const int tid = threadIdx.x;
    const int h = blockIdx.x >> 3, c = blockIdx.x & 7;
    const int tb = blockIdx.y * 16;        // row base within chunk (0..112)
    const int SMAX = tb + 16;              // columns needed: s < SMAX

    const int hc128 = (h << 10) + c * 128;
    const int hcS   = (h * 8 + c) * 256;

    if (tid < 256) z_lds[tid] = z_prev[hcS + tid];

    // staging identity (512 threads)
    const int fidx = tid & 31;       // f within 32-slice
    const int srow = tid >> 5;       // 0..15
    const int frow = tid >> 6;       // 0..7 (Sst)
    const int sdd  = tid & 63;       // d (Sst)

    // A-wave identity (tid < 256): rows 2*tt.., cols 4*ss..
    const int tt = tid >> 5;         // 0..7 -> rows 2tt, 2tt+1
    const int ss = tid & 31;         // cols ss*4..
    const bool ssActive = (ss * 4) < SMAX;
    // inter-wave identity (tid >= 256): d, row group tg*4..
    const int u = tid & 255;
    const int d = u & 63, tg = u >> 6;   // tg 0..3 -> rows tg*4..tg*4+3

    float acc[2][4];
    float acc2[4];
    float den_acc = 0.f;
#pragma unroll
    for (int i = 0; i < 2; ++i)
#pragma unroll
        for (int j = 0; j < 4; ++j) acc[i][j] = 0.f;
#pragma unroll
    for (int i = 0; i < 4; ++i) acc2[i] = 0.f;

    // ---- prefetch registers (13 floats) ----
    float r_q0, r_k[8], r_s[4];
#define LOAD_SLICE(F0)                                                        \
    do {                                                                      \
        r_q0 = phi_q[((hc128 + tb + srow) << 8) + (F0) + fidx];               \
        _Pragma("unroll")                                                     \
        for (int k = 0; k < 8; ++k) {                                         \
            int s_ = srow + 16 * k;                                           \
            r_k[k] = (s_ < SMAX) ? phi_k[((hc128 + s_) << 8) + (F0) + fidx]   \
                                 : 0.f;                                       \
        }                                                                     \
        _Pragma("unroll")                                                     \
        for (int k = 0; k < 4; ++k)                                           \
            r_s[k] = S_prev[((hcS + (F0) + frow + 8 * k) << 6) + sdd];        \
    } while (0)

    LOAD_SLICE(0);

    for (int ft = 0; ft < 8; ++ft) {
        const int f0 = ft * 32;
        __syncthreads();                   // prev compute done reading LDS
        phq_t[fidx][srow] = r_q0;
#pragma unroll
        for (int k = 0; k < 8; ++k) phk_t[fidx][srow + 16 * k] = r_k[k];
#pragma unroll
        for (int k = 0; k < 4; ++k) Sst[frow + 8 * k][sdd] = r_s[k];
        __syncthreads();
        if (ft < 7) LOAD_SLICE(f0 + 32);   // latency hides under compute

        if (tid < 256) {
            if (ssActive) {
#pragma unroll 4
                for (int f = 0; f < 32; ++f) {
                    float a0 = phq_t[f][tt * 2];
                    float a1 = phq_t[f][tt * 2 + 1];
                    float4 bv = *(const float4*)&phk_t[f][ss * 4];
                    acc[0][0] += a0 * bv.x; acc[0][1] += a0 * bv.y;
                    acc[0][2] += a0 * bv.z; acc[0][3] += a0 * bv.w;
                    acc[1][0] += a1 * bv.x; acc[1][1] += a1 * bv.y;
                    acc[1][2] += a1 * bv.z; acc[1][3] += a1 * bv.w;
                }
            }
        } else {
#pragma unroll 4
            for (int f = 0; f < 32; ++f) {
                float sval = Sst[f][d];
                float4 a = *(const float4*)&phq_t[f][tg * 4];
                acc2[0] += a.x * sval; acc2[1] += a.y * sval;
                acc2[2] += a.z * sval; acc2[3] += a.w * sval;
            }
            if (u < 16) {
#pragma unroll
                for (int f = 0; f < 32; ++f)
                    den_acc += phq_t[f][u] * z_lds[f0 + f];
            }
        }
    }
#undef LOAD_SLICE

    // ---- handoff ----
    if (tid < 256) {
        if (ssActive) {
#pragma unroll
            for (int i = 0; i < 2; ++i) {
                float4 o = make_float4(acc[i][0], acc[i][1], acc[i][2], acc[i][3]);
                *(float4*)&A_lds[(tt * 2 + i) * 132 + ss * 4] = o;
            }
        }
    } else {
#pragma unroll
        for (int i = 0; i < 4; ++i)
            ctx_lds[tg * 4 + i][d] = acc2[i];
        if (u < 16) den_lds[u] = den_acc;
    }
    __syncthreads();

    // ---- masked A*V tail + divide + store (V from global, coalesced) ----
    const int dd = tid & 63;
    const int rg = tid >> 6;               // 0..7, rows rg*2, rg*2+1
    const float* vp = qkv + (size_t)(c * 128) * 1536 + 1024 + h * 64 + dd;
#pragma unroll
    for (int i = 0; i < 2; ++i) {
        int tl = rg * 2 + i;               // local row 0..15
        int tcr = tb + tl;                 // row within chunk
        float ctx = ctx_lds[tl][dd];
        float den = den_lds[tl];
        for (int s = 0; s <= tcr; ++s) {
            float a = A_lds[tl * 132 + s];
            ctx += a * vp[(size_t)s * 1536];
            den += a;
        }
        attn[(c * 128 + tcr) * 512 + h * 64 + dd] = ctx / fmaxf(den, 1e-6f);
    }
}

extern "C" void kernel_launch(void* const* d_in, const int* in_sizes, int n_in,
                              void* d_out, int out_size, void* d_ws, size_t ws_size,
                              hipStream_t stream)
{
    const float* x      = (const float*)d_in[0];
    const float* W_qkv  = (const float*)d_in[1];
    const float* b_qkv  = (const float*)d_in[2];
    const float* W_out  = (const float*)d_in[3];
    const float* b_out  = (const float*)d_in[4];
    const float* omega  = (const float*)d_in[5];
    const float* W_poly = (const float*)d_in[6];
    const float* qn     = (const float*)d_in[7];
    const float* qw     = (const float*)d_in[8];
    float* out = (float*)d_out;

    float* ws     = (float*)d_ws;
    float* qkv    = ws;                     // 1024*1536
    float* phi_q  = qkv + 1572864;          // 8*1024*256
    float* phi_k  = phi_q + 2097152;        // 8*1024*256
    float* S_c    = phi_k + 2097152;        // 8*8*256*64
    float* z_c    = S_c + 1048576;          // 8*8*256
    float* S_p    = z_c + 16384;            // 8*8*256*64
    float* z_p    = S_p + 1048576;          // 8*8*256
    float* attn   = z_p + 16384;            // 1024*512
    float* p_qkv  = attn + 524288;          // 4*1024*1536
    float* p_out  = p_qkv + 6291456;        // 4*1024*512

    gemm_part_kernel<<<dim3(24, 16, 4), 256, 0, stream>>>(x, W_qkv, p_qkv, 1024, 1536, 512, 128);
    reduce_bias_kernel<<<1536, 256, 0, stream>>>(p_qkv, b_qkv, qkv, 1572864, 1536, 4);
    features_kernel<<<2048, 256, 0, stream>>>(qkv, omega, W_poly, qn, qw, phi_q, phi_k);
    chunksum_kernel<<<256, 256, 0, stream>>>(phi_k, qkv, S_c, z_c);
    scan_kernel<<<512, 256, 0, stream>>>(S_c, z_c, S_p, z_p);
    attn_kernel<<<dim3(64, 8), 512, 0, stream>>>(phi_q, phi_k, qkv, S_p, z_p, attn);
    gemm_part_kernel<<<dim3(8, 16, 4), 256, 0, stream>>>(attn, W_out, p_out, 1024, 512, 512, 128);
    reduce_bias_kernel<<<512, 256, 0, stream>>>(p_out, b_out, out, 524288, 512, 4);
}